// Round 10
// baseline (80.169 us; speedup 1.0000x reference)
//
#include <hip/hip_runtime.h>

// Bilateral 3x3, sigma_color == sigma_space == 0.8, reflect-101.
// Exact simplifications: normalizations cancel; fused single exp2 per tap;
// center tap folded (w==1). Raw v_exp_f32 / v_rcp_f32 (args safely ranged).
// This round: wave-wide rows (64 lanes x 8 px = 512 = full row), halos via
// __shfl from neighbor lanes (no scalar halo loads); 4 output rows per thread
// with a rolling 3-row register window (row loads per output row 1.5).
#define HW 512

typedef float vfloat4 __attribute__((ext_vector_type(4)));

__global__ __launch_bounds__(256) void bilateral3x3(const float* __restrict__ in,
                                                    float* __restrict__ out,
                                                    int nwaves) {
    int wid  = blockIdx.x * 4 + ((int)threadIdx.x >> 6);
    int lane = (int)threadIdx.x & 63;
    if (wid >= nwaves) return;

    int rg    = wid & 127;          // 128 groups of 4 rows per plane
    int plane = wid >> 7;           // 24 planes
    int r0    = rg << 2;
    int x0    = lane << 3;

    const float* p = in + (size_t)plane * (HW * HW);

    float R0[10], R1[10], R2[10];
    auto loadrow = [&](float* w, int r) {
        const float* rp = p + (size_t)r * HW + x0;
        vfloat4 a = *reinterpret_cast<const vfloat4*>(rp);
        vfloat4 b = *reinterpret_cast<const vfloat4*>(rp + 4);
        // halos from neighbor lanes; wave == full row, so only lane 0/63
        // hit the x-reflect, and those values are in-register already.
        float lh = __shfl_up(b.w, 1);    // lane l-1's pixel x0-1
        float rh = __shfl_down(a.x, 1);  // lane l+1's pixel x0+8
        w[0] = (lane == 0)  ? a.y : lh;  // reflect-101: x=-1  -> x=1
        w[9] = (lane == 63) ? b.z : rh;  // reflect-101: x=512 -> x=510
        w[1] = a.x; w[2] = a.y; w[3] = a.z; w[4] = a.w;
        w[5] = b.x; w[6] = b.y; w[7] = b.z; w[8] = b.w;
    };

    const float nC = -1.1271055f;   // -(1/(2*0.8^2)) * log2(e)

    auto dorow = [&](const float* T, const float* M, const float* Bo, float* op) {
        float res[8];
        #pragma unroll
        for (int j = 0; j < 8; ++j) {
            float c = M[j + 1];
            float num = c;          // center tap: w == 1
            float den = 1.0f;
            #pragma unroll
            for (int dx = 0; dx < 3; ++dx) {
                float spd = (float)(1 + (dx - 1) * (dx - 1));
                {   // top row
                    float pv = T[j + dx];
                    float d  = pv - c;
                    float w  = __builtin_amdgcn_exp2f(fmaf(d, d, spd) * nC);
                    num = fmaf(w, pv, num); den += w;
                }
                {   // bottom row
                    float pv = Bo[j + dx];
                    float d  = pv - c;
                    float w  = __builtin_amdgcn_exp2f(fmaf(d, d, spd) * nC);
                    num = fmaf(w, pv, num); den += w;
                }
                if (dx != 1) {  // middle row, center skipped
                    float pv = M[j + dx];
                    float d  = pv - c;
                    float w  = __builtin_amdgcn_exp2f(fmaf(d, d, 1.0f) * nC);
                    num = fmaf(w, pv, num); den += w;
                }
            }
            res[j] = num * __builtin_amdgcn_rcpf(den);
        }
        vfloat4 o0 = {res[0], res[1], res[2], res[3]};
        vfloat4 o1 = {res[4], res[5], res[6], res[7]};
        __builtin_nontemporal_store(o0, reinterpret_cast<vfloat4*>(op));
        __builtin_nontemporal_store(o1, reinterpret_cast<vfloat4*>(op) + 1);
    };

    // reflect-101 in y
    int ym = (r0 == 0)   ? 1   : r0 - 1;
    int yb = (r0 == 508) ? 510 : r0 + 4;

    float* op = out + (size_t)plane * (HW * HW) + (size_t)r0 * HW + x0;

    loadrow(R0, ym);
    loadrow(R1, r0);
    loadrow(R2, r0 + 1);
    dorow(R0, R1, R2, op);              // out row r0
    loadrow(R0, r0 + 2);
    dorow(R1, R2, R0, op + HW);         // out row r0+1
    loadrow(R1, r0 + 3);
    dorow(R2, R0, R1, op + 2 * HW);     // out row r0+2
    loadrow(R2, yb);
    dorow(R0, R1, R2, op + 3 * HW);     // out row r0+3
}

extern "C" void kernel_launch(void* const* d_in, const int* in_sizes, int n_in,
                              void* d_out, int out_size, void* d_ws, size_t ws_size,
                              hipStream_t stream) {
    const float* in = (const float*)d_in[0];
    float* out = (float*)d_out;
    int total = in_sizes[0];            // 8*3*512*512
    int nwaves = total >> 11;           // one wave = 512 px x 4 rows = 2048 px
    int blocks = (nwaves + 3) / 4;      // 4 waves per block
    bilateral3x3<<<blocks, 256, 0, stream>>>(in, out, nwaves);
}